// Round 6
// baseline (397.214 us; speedup 1.0000x reference)
//
#include <hip/hip_runtime.h>

#define B   32
#define L   1024
#define MN  512
#define SD  256
#define VD  64
#define DM  256
#define D3  192
#define NH  8
#define DK  32
#define RMAX 30
#define NREL 61
#define SPAD 518   // MN + 6 (3-zero pad each side) for im2col conv windows

typedef __attribute__((ext_vector_type(8))) __bf16 bf16x8;
typedef __attribute__((ext_vector_type(4))) float  f32x4;

static __device__ __forceinline__ ushort f2bf(float f) {
  unsigned u = __float_as_uint(f);
  unsigned r = (u + 0x7FFFu + ((u >> 16) & 1u)) >> 16;
  return (ushort)r;
}
static __device__ __forceinline__ bf16x8 ldbf8(const ushort* p) {
  return __builtin_bit_cast(bf16x8, *(const uint4*)p);
}
static __device__ __forceinline__ float fexp2(float x) {
  return __builtin_amdgcn_exp2f(x);
}

// ---------------------------------------------------------------------------
// f32 -> bf16 bulk convert. size must be multiple of 1024.
// ---------------------------------------------------------------------------
__global__ __launch_bounds__(256) void tobf_kernel(
    const float* __restrict__ src, ushort* __restrict__ dst) {
  int i = (blockIdx.x * 256 + threadIdx.x) * 4;
  float4 v = *(const float4*)(src + i);
  *(ushort4*)(dst + i) = make_ushort4(f2bf(v.x), f2bf(v.y), f2bf(v.z), f2bf(v.w));
}

// Fused small-weight converts (Wg 16, Wq 64, Wk 48, Wv 48, fcw 64 blocks).
__global__ __launch_bounds__(256) void tobf5_kernel(
    const float* __restrict__ s0, ushort* __restrict__ d0,
    const float* __restrict__ s1, ushort* __restrict__ d1,
    const float* __restrict__ s2, ushort* __restrict__ d2,
    const float* __restrict__ s3, ushort* __restrict__ d3,
    const float* __restrict__ s4, ushort* __restrict__ d4) {
  int blk = blockIdx.x;
  const float* s; ushort* d; int base;
  if (blk < 16)       { s = s0; d = d0; base = blk; }
  else if (blk < 80)  { s = s1; d = d1; base = blk - 16; }
  else if (blk < 128) { s = s2; d = d2; base = blk - 80; }
  else if (blk < 176) { s = s3; d = d3; base = blk - 128; }
  else                { s = s4; d = d4; base = blk - 176; }
  int i = (base * 256 + threadIdx.x) * 4;
  float4 v = *(const float4*)(s + i);
  *(ushort4*)(d + i) = make_ushort4(f2bf(v.x), f2bf(v.y), f2bf(v.z), f2bf(v.w));
}

// ---------------------------------------------------------------------------
// MFMA projection: wave = 16 rows, 16 col-tiles, CIN/32 k-steps.
// OMODE: 0 = f32 [row][DM]; 1 = bf16 [row][DM]; 2 = bf16 V^T [b][h][dk][s];
//        3 = bf16 K [b][h][s][dk]; 4 = bf16 Q head-major [b][h][q][dk]
// AF32: A operand read as f32 and converted in-kernel (saves a tobf pass).
// ---------------------------------------------------------------------------
template<int CIN, int OMODE, int ACT, int AF32>
__global__ __launch_bounds__(256, 2) void proj_mfma_kernel(
    const void* __restrict__ Xv, const ushort* __restrict__ Wb, void* Yv) {
  const int tid = threadIdx.x;
  const int wave = tid >> 6, lane = tid & 63;
  const int q15 = lane & 15, quad = lane >> 4;
  const int row0 = blockIdx.x * 64 + wave * 16;
  constexpr int KS = CIN / 32;

  f32x4 acc[16];
#pragma unroll
  for (int t = 0; t < 16; ++t) acc[t] = (f32x4){0.f, 0.f, 0.f, 0.f};

  const ushort* abase = (const ushort*)Xv + (size_t)(row0 + q15) * CIN + quad * 8;
  const float*  fbase = (const float*)Xv + (size_t)(row0 + q15) * CIN + quad * 8;
  const ushort* bbase = Wb + (size_t)q15 * CIN + quad * 8;
#pragma unroll 2
  for (int ks = 0; ks < KS; ++ks) {
    bf16x8 af;
    if constexpr (AF32) {
      float4 u0 = *(const float4*)(fbase + ks * 32);
      float4 u1 = *(const float4*)(fbase + ks * 32 + 4);
      uint4 p;
      p.x = (uint)f2bf(u0.x) | ((uint)f2bf(u0.y) << 16);
      p.y = (uint)f2bf(u0.z) | ((uint)f2bf(u0.w) << 16);
      p.z = (uint)f2bf(u1.x) | ((uint)f2bf(u1.y) << 16);
      p.w = (uint)f2bf(u1.z) | ((uint)f2bf(u1.w) << 16);
      af = __builtin_bit_cast(bf16x8, p);
    } else {
      af = ldbf8(abase + ks * 32);
    }
#pragma unroll
    for (int t = 0; t < 16; ++t) {
      bf16x8 bf = ldbf8(bbase + (size_t)t * 16 * CIN + ks * 32);
      acc[t] = __builtin_amdgcn_mfma_f32_16x16x32_bf16(af, bf, acc[t], 0, 0, 0);
    }
  }
#pragma unroll
  for (int reg = 0; reg < 4; ++reg) {
    const int row = row0 + quad * 4 + reg;
#pragma unroll
    for (int t = 0; t < 16; ++t) {
      int col = t * 16 + q15;
      float v = acc[t][reg];
      if (ACT == 1) v = 1.f / (1.f + __expf(-v));
      if (OMODE == 0) {
        ((float*)Yv)[(size_t)row * DM + col] = v;
      } else if (OMODE == 1) {
        ((ushort*)Yv)[(size_t)row * DM + col] = f2bf(v);
      } else if (OMODE == 2) {
        int b_ = row >> 9, s = row & 511;
        int h = t >> 1, dk = (t & 1) * 16 + q15;
        ((ushort*)Yv)[((size_t)((b_ * NH + h) * DK + dk)) * MN + s] = f2bf(v);
      } else if (OMODE == 3) {
        int b_ = row >> 9, s = row & 511;
        int h = col >> 5, dk = col & 31;
        ((ushort*)Yv)[((size_t)((b_ * NH + h) * MN + s)) * DK + dk] = f2bf(v);
      } else {
        int b_ = row >> 10, q = row & 1023;
        int h = col >> 5, dk = col & 31;
        ((ushort*)Yv)[((size_t)((b_ * NH + h) * L + q)) * DK + dk] = f2bf(v);
      }
    }
  }
}

// ---------------------------------------------------------------------------
// im2col conv: split-bf16 hi/lo padded planes (keeps xm f32-grade).
// R13: 256-thread flat launch (was 16576 x 64-thread blocks).
// ---------------------------------------------------------------------------
__global__ __launch_bounds__(256) void splitpad_kernel(
    const float* __restrict__ xv, ushort* __restrict__ xp) {
  int i = blockIdx.x * 256 + threadIdx.x;
  if (i >= B * SPAD * VD) return;
  int c = i & 63;
  int bp = i >> 6;
  int b_ = bp / SPAD, p = bp - b_ * SPAD;
  int s = p - 3;
  float v = (s >= 0 && s < MN) ? xv[((size_t)b_ * MN + s) * VD + c] : 0.f;
  ushort hi = f2bf(v);
  float vh = __uint_as_float((uint)hi << 16);
  ushort lo = f2bf(v - vh);
  xp[i] = hi;
  xp[(size_t)B * SPAD * VD + i] = lo;
}

// Wbig [192][448] bf16: row o of scale K has taps at centered k-offsets.
__global__ __launch_bounds__(448) void wbig_kernel(
    const float* __restrict__ w3, const float* __restrict__ w5,
    const float* __restrict__ w7, ushort* __restrict__ wb) {
  const int o = blockIdx.x;        // 0..191
  const int j = threadIdx.x;       // 0..447
  const int k7 = j >> 6, i = j & 63;
  const int scale = o >> 6, oo = o & 63;
  float v = 0.f;
  if (scale == 0) {
    int k = k7 - 2; if (k >= 0 && k < 3) v = w3[((size_t)oo * VD + i) * 3 + k];
  } else if (scale == 1) {
    int k = k7 - 1; if (k >= 0 && k < 5) v = w5[((size_t)oo * VD + i) * 5 + k];
  } else {
    v = w7[((size_t)oo * VD + i) * 7 + k7];
  }
  wb[(size_t)o * 448 + j] = f2bf(v);
}

// conv GEMM: M=16384 rows (windows at stride VD in padded buffer),
// N=192, K=448 (x2 for hi+lo). 16 rows/block, 4 waves x 3 col-tiles.
__global__ __launch_bounds__(256, 4) void conv_mfma_kernel(
    const ushort* __restrict__ Xp, const ushort* __restrict__ Wb,
    const float* __restrict__ b3, const float* __restrict__ b5,
    const float* __restrict__ b7, float* __restrict__ xm) {
  const int tid = threadIdx.x;
  const int wave = tid >> 6, lane = tid & 63;
  const int q15 = lane & 15, quad = lane >> 4;
  const int row0 = blockIdx.x * 16;
  const int b_ = row0 >> 9, s0 = row0 & 511;

  f32x4 acc[3];
#pragma unroll
  for (int t = 0; t < 3; ++t) acc[t] = (f32x4){0.f, 0.f, 0.f, 0.f};

  const ushort* hbase = Xp + ((size_t)b_ * SPAD + s0 + q15) * VD + quad * 8;
  const ushort* lbase = hbase + (size_t)B * SPAD * VD;
  const ushort* wbase = Wb + ((size_t)wave * 48 + q15) * 448 + quad * 8;

#pragma unroll 2
  for (int ks = 0; ks < 14; ++ks) {
    bf16x8 ah = ldbf8(hbase + ks * 32);
    bf16x8 al = ldbf8(lbase + ks * 32);
#pragma unroll
    for (int t = 0; t < 3; ++t) {
      bf16x8 bf = ldbf8(wbase + (size_t)t * 16 * 448 + ks * 32);
      acc[t] = __builtin_amdgcn_mfma_f32_16x16x32_bf16(ah, bf, acc[t], 0, 0, 0);
      acc[t] = __builtin_amdgcn_mfma_f32_16x16x32_bf16(al, bf, acc[t], 0, 0, 0);
    }
  }
#pragma unroll
  for (int t = 0; t < 3; ++t) {
    const int col = (wave * 3 + t) * 16 + q15;
    const float bias = col < 64 ? b3[col] : (col < 128 ? b5[col - 64] : b7[col - 128]);
#pragma unroll
    for (int reg = 0; reg < 4; ++reg) {
      const int row = row0 + quad * 4 + reg;
      xm[(size_t)row * D3 + col] = acc[t][reg] + bias;
    }
  }
}

// ---------------------------------------------------------------------------
// pos_sum[j, d] = sum_i emb[clip(j-i, -R, R) + R, d]
// ---------------------------------------------------------------------------
__global__ __launch_bounds__(D3) void possum_kernel(
    const float* __restrict__ emb, float* __restrict__ psum) {
  const int j = blockIdx.x, d = threadIdx.x;
  float acc = 0.f;
  for (int r = 0; r < NREL; ++r) {
    int v = r - RMAX;
    int cnt;
    if (r == 0)             cnt = max(0, MN - (j + RMAX));
    else if (r == NREL - 1) cnt = max(0, j - RMAX + 1);
    else                    cnt = (j - v >= 0 && j - v < MN) ? 1 : 0;
    acc += (float)cnt * emb[(size_t)r * D3 + d];
  }
  psum[(size_t)j * D3 + d] = acc;
}

// ---------------------------------------------------------------------------
// rel-pos-enc closed form (elementwise), output bf16 (feeds K/V proj only)
// ---------------------------------------------------------------------------
__global__ __launch_bounds__(D3) void pe_kernel(
    const float* __restrict__ xm, const float* __restrict__ psum,
    const float* __restrict__ emb, const float* __restrict__ dww,
    const float* __restrict__ dwb, ushort* __restrict__ xpe) {
  const int bb_ = blockIdx.x / MN, j = blockIdx.x % MN;
  const int d = threadIdx.x;
  const size_t base = ((size_t)bb_ * MN + j) * D3 + d;
  float xc = xm[base];
  float fC = xc + emb[(size_t)RMAX * D3 + d];
  float fL = (j > 0)      ? xm[base - D3] + emb[(size_t)(RMAX - 1) * D3 + d] : 0.f;
  float fR = (j < MN - 1) ? xm[base + D3] + emb[(size_t)(RMAX + 1) * D3 + d] : 0.f;
  float dc = fL * dww[d * 3 + 0] + fC * dww[d * 3 + 1] + fR * dww[d * 3 + 2] + dwb[d];
  xpe[base] = f2bf(xc + (psum[(size_t)j * D3 + d] - fC + dc) * (1.f / MN));
}

// ---------------------------------------------------------------------------
// MFMA flash attention (R13: two-pass softmax + batched P staging).
// R12 post-mortem: clean traffic (FETCH 33MB) but dur unchanged at 66.5us ->
// pure latency chain: per c-iter QK -> 32-deep fmax -> 2 serial shfl ->
// alpha/rescale -> per-g {exp,pack,LDS write,wait,read,PV}.
// R13: pass1 = exact row max over all 512 keys (QK only, raw max, 2 shfl
// TOTAL); pass2 = QK recompute (L1-hot K, idle MFMA pipe) -> exp2 directly
// via fma(s,sc2,-m) with NO cross-lane dependency -> batched 128-key P rows:
// 8 ds_write then 4 ds_read_b128 (16B-aligned now) then 8 PV per tile.
// Same (256,3) envelope as the 84-VGPR build; spill tripwire = WRITE_SIZE.
// ---------------------------------------------------------------------------
#define PSTRIDE 136  // 128 keys + 8 pad (272B rows: 16B-aligned, 2-way bank)
__global__ __launch_bounds__(256, 3) void attn_mfma_kernel(
    const ushort* __restrict__ Qb, const ushort* __restrict__ Kb,
    const ushort* __restrict__ Vt, ushort* __restrict__ Ao) {
  const int blk = blockIdx.x;
  const int bh = blk & 255;        // low bits -> fixed XCD per (b,h)
  const int qc = blk >> 8;         // 0..7 (128 q rows per block)
  const int h  = bh & 7;
  const int b_ = bh >> 3;
  const int tid = threadIdx.x;
  const int wave = tid >> 6, lane = tid & 63;
  const int q15 = lane & 15, quad = lane >> 4;
  const int q0 = qc * 128 + wave * 32;

  __shared__ __align__(16) ushort Plds[4][2][16][PSTRIDE];
  ushort* prowA = &Plds[wave][0][q15][0];
  ushort* prowB = &Plds[wave][1][q15][0];

  // Q head-major: contiguous 64B rows, adjacent rows share 128B lines
  const ushort* qrow = Qb + ((size_t)((b_ * NH + h) * L) + q0 + q15) * DK + quad * 8;
  const bf16x8 qfA = ldbf8(qrow);
  const bf16x8 qfB = ldbf8(qrow + (size_t)16 * DK);

  const ushort* kbase = Kb + (((size_t)(b_ * NH + h) * MN) + q15) * DK + quad * 8;
  const ushort* vbase = Vt + ((size_t)((b_ * NH + h) * DK) + q15) * MN;

  // softmax in exp2 space: p = exp2(s*sc2 - m), sc2 = log2(e)/sqrt(32)
  const float sc2 = 0.17677669529663687f * 1.4426950408889634f;

  // ---- pass 1: exact row max (raw scores; scale once at the end) ----
  float mA = -1e30f, mB = -1e30f;
#pragma unroll
  for (int c = 0; c < 4; ++c) {
#pragma unroll
    for (int t = 0; t < 8; ++t) {
      bf16x8 af = ldbf8(kbase + (size_t)(c * 128 + t * 16) * DK);
      f32x4 z = {0.f, 0.f, 0.f, 0.f};
      f32x4 sa = __builtin_amdgcn_mfma_f32_16x16x32_bf16(af, qfA, z, 0, 0, 0);
      f32x4 sb = __builtin_amdgcn_mfma_f32_16x16x32_bf16(af, qfB, z, 0, 0, 0);
      mA = fmaxf(mA, fmaxf(fmaxf(sa[0], sa[1]), fmaxf(sa[2], sa[3])));
      mB = fmaxf(mB, fmaxf(fmaxf(sb[0], sb[1]), fmaxf(sb[2], sb[3])));
    }
  }
  mA = fmaxf(mA, __shfl_xor(mA, 16));
  mB = fmaxf(mB, __shfl_xor(mB, 16));
  mA = fmaxf(mA, __shfl_xor(mA, 32));
  mB = fmaxf(mB, __shfl_xor(mB, 32));
  mA *= sc2;
  mB *= sc2;

  // ---- pass 2: exp + PV with known max (no cross-lane in the chain) ----
  f32x4 o0A = {0.f, 0.f, 0.f, 0.f}, o1A = {0.f, 0.f, 0.f, 0.f};
  f32x4 o0B = {0.f, 0.f, 0.f, 0.f}, o1B = {0.f, 0.f, 0.f, 0.f};
  float lA = 0.f, lB = 0.f;

#pragma unroll
  for (int c = 0; c < 4; ++c) {
    const int kb0 = c * 128;
    bf16x8 av[8];
#pragma unroll
    for (int g = 0; g < 4; ++g) {
      av[g * 2]     = ldbf8(vbase + (size_t)(kb0 + g * 32 + quad * 8));
      av[g * 2 + 1] = ldbf8(vbase + (size_t)16 * MN + (kb0 + g * 32 + quad * 8));
    }
    f32x4 sA[8], sB[8];
#pragma unroll
    for (int t = 0; t < 8; ++t) {
      bf16x8 af = ldbf8(kbase + (size_t)(kb0 + t * 16) * DK);
      f32x4 z = {0.f, 0.f, 0.f, 0.f};
      sA[t] = __builtin_amdgcn_mfma_f32_16x16x32_bf16(af, qfA, z, 0, 0, 0);
      sB[t] = __builtin_amdgcn_mfma_f32_16x16x32_bf16(af, qfB, z, 0, 0, 0);
    }
    // tile A: exp+pack all 128 keys -> 8 writes -> 4 reads -> 8 PV
#pragma unroll
    for (int g = 0; g < 4; ++g) {
#pragma unroll
      for (int tp = 0; tp < 2; ++tp) {
        int t = 2 * g + tp;
        float a0 = fexp2(fmaf(sA[t][0], sc2, -mA));
        float a1 = fexp2(fmaf(sA[t][1], sc2, -mA));
        float a2 = fexp2(fmaf(sA[t][2], sc2, -mA));
        float a3 = fexp2(fmaf(sA[t][3], sc2, -mA));
        lA += (a0 + a1) + (a2 + a3);
        uint u01 = __builtin_amdgcn_perm(__float_as_uint(a1), __float_as_uint(a0), 0x07060302u);
        uint u23 = __builtin_amdgcn_perm(__float_as_uint(a3), __float_as_uint(a2), 0x07060302u);
        *(uint2*)(prowA + g * 32 + tp * 16 + quad * 4) = make_uint2(u01, u23);
      }
    }
#pragma unroll
    for (int g = 0; g < 4; ++g) {
      bf16x8 bfA = ldbf8(prowA + g * 32 + quad * 8);
      o0A = __builtin_amdgcn_mfma_f32_16x16x32_bf16(av[g * 2],     bfA, o0A, 0, 0, 0);
      o1A = __builtin_amdgcn_mfma_f32_16x16x32_bf16(av[g * 2 + 1], bfA, o1A, 0, 0, 0);
    }
    // tile B
#pragma unroll
    for (int g = 0; g < 4; ++g) {
#pragma unroll
      for (int tp = 0; tp < 2; ++tp) {
        int t = 2 * g + tp;
        float b0 = fexp2(fmaf(sB[t][0], sc2, -mB));
        float b1 = fexp2(fmaf(sB[t][1], sc2, -mB));
        float b2 = fexp2(fmaf(sB[t][2], sc2, -mB));
        float b3 = fexp2(fmaf(sB[t][3], sc2, -mB));
        lB += (b0 + b1) + (b2 + b3);
        uint u01 = __builtin_amdgcn_perm(__float_as_uint(b1), __float_as_uint(b0), 0x07060302u);
        uint u23 = __builtin_amdgcn_perm(__float_as_uint(b3), __float_as_uint(b2), 0x07060302u);
        *(uint2*)(prowB + g * 32 + tp * 16 + quad * 4) = make_uint2(u01, u23);
      }
    }
#pragma unroll
    for (int g = 0; g < 4; ++g) {
      bf16x8 bfB = ldbf8(prowB + g * 32 + quad * 8);
      o0B = __builtin_amdgcn_mfma_f32_16x16x32_bf16(av[g * 2],     bfB, o0B, 0, 0, 0);
      o1B = __builtin_amdgcn_mfma_f32_16x16x32_bf16(av[g * 2 + 1], bfB, o1B, 0, 0, 0);
    }
  }
  lA += __shfl_xor(lA, 16); lA += __shfl_xor(lA, 32);
  lB += __shfl_xor(lB, 16); lB += __shfl_xor(lB, 32);
  float rA = 1.f / lA, rB = 1.f / lB;
  // Ao head-major: each 128B line (rows q,q+1) fully written by this wave
  ushort* obA = Ao + ((size_t)((b_ * NH + h) * L) + q0 + q15) * DK + quad * 4;
  *(ushort4*)(obA)      = make_ushort4(f2bf(o0A[0] * rA), f2bf(o0A[1] * rA),
                                       f2bf(o0A[2] * rA), f2bf(o0A[3] * rA));
  *(ushort4*)(obA + 16) = make_ushort4(f2bf(o1A[0] * rA), f2bf(o1A[1] * rA),
                                       f2bf(o1A[2] * rA), f2bf(o1A[3] * rA));
  ushort* obB = obA + (size_t)16 * DK;
  *(ushort4*)(obB)      = make_ushort4(f2bf(o0B[0] * rB), f2bf(o0B[1] * rB),
                                       f2bf(o0B[2] * rB), f2bf(o0B[3] * rB));
  *(ushort4*)(obB + 16) = make_ushort4(f2bf(o1B[0] * rB), f2bf(o1B[1] * rB),
                                       f2bf(o1B[2] * rB), f2bf(o1B[3] * rB));
}

// ---------------------------------------------------------------------------
// Final via MFMA: fc (bf16 MFMA) + Gamma gating + residual + LayerNorm.
// Ao is head-major [b][h][q][dk]; with KS=8, k-chunk ks == head ks,
// so A-loads are abase + ks*L*DK (uniform stride). fcwb unchanged.
// ---------------------------------------------------------------------------
__global__ __launch_bounds__(256, 2) void final_mfma_kernel(
    const ushort* __restrict__ Ao, const ushort* __restrict__ fcwb,
    const float* __restrict__ fcb, const float* __restrict__ G,
    const float* __restrict__ Xs, const float* __restrict__ lnw,
    const float* __restrict__ lnb, float* __restrict__ out) {
  const int tid = threadIdx.x;
  const int wave = tid >> 6, lane = tid & 63;
  const int q15 = lane & 15, quad = lane >> 4;
  const int row0 = blockIdx.x * 64 + wave * 16;
  const int brow = row0 >> 10;            // batch (blocks are 64-row aligned)
  const int srow = (row0 & 1023) + q15;   // q within batch

  f32x4 acc[16];
#pragma unroll
  for (int t = 0; t < 16; ++t) acc[t] = (f32x4){0.f, 0.f, 0.f, 0.f};

  const ushort* abase = Ao + ((size_t)(brow * NH) * L + srow) * DK + quad * 8;
  const ushort* bbase = fcwb + (size_t)q15 * DM + quad * 8;
#pragma unroll 2
  for (int ks = 0; ks < 8; ++ks) {
    bf16x8 af = ldbf8(abase + (size_t)ks * L * DK);
#pragma unroll
    for (int t = 0; t < 16; ++t) {
      bf16x8 bf = ldbf8(bbase + (size_t)t * 16 * DM + ks * 32);
      acc[t] = __builtin_amdgcn_mfma_f32_16x16x32_bf16(af, bf, acc[t], 0, 0, 0);
    }
  }
#pragma unroll
  for (int reg = 0; reg < 4; ++reg) {
    const int grow = row0 + quad * 4 + reg;
    const int b_ = grow >> 10;
    const int gl = (grow & 1023) & 511;
    const float* gbase = G + ((size_t)b_ * MN + gl) * DM + q15;
    const float* xbase = Xs + (size_t)grow * SD + q15;
    float vv[16];
    float s1 = 0.f, s2 = 0.f;
#pragma unroll
    for (int t = 0; t < 16; ++t) {
      int col = t * 16 + q15;
      float fcv = acc[t][reg] + fcb[col];
      float v = xbase[t * 16] + gbase[t * 16] * fcv;
      vv[t] = v; s1 += v; s2 += v * v;
    }
    s1 += __shfl_xor(s1, 1); s2 += __shfl_xor(s2, 1);
    s1 += __shfl_xor(s1, 2); s2 += __shfl_xor(s2, 2);
    s1 += __shfl_xor(s1, 4); s2 += __shfl_xor(s2, 4);
    s1 += __shfl_xor(s1, 8); s2 += __shfl_xor(s2, 8);
    float mu = s1 * (1.f / DM);
    float var = s2 * (1.f / DM) - mu * mu;
    float rs = rsqrtf(var + 1e-5f);
    float* obase = out + (size_t)grow * DM + q15;
#pragma unroll
    for (int t = 0; t < 16; ++t) {
      int col = t * 16 + q15;
      obase[t * 16] = (vv[t] - mu) * rs * lnw[col] + lnb[col];
    }
  }
}

// ---------------------------------------------------------------------------
extern "C" void kernel_launch(void* const* d_in, const int* in_sizes, int n_in,
                              void* d_out, int out_size, void* d_ws, size_t ws_size,
                              hipStream_t stream) {
  const float* x_spatial  = (const float*)d_in[0];
  const float* x_velocity = (const float*)d_in[1];
  const float* Wg   = (const float*)d_in[2];
  const float* w3   = (const float*)d_in[3];
  const float* b3   = (const float*)d_in[4];
  const float* w5   = (const float*)d_in[5];
  const float* b5   = (const float*)d_in[6];
  const float* w7   = (const float*)d_in[7];
  const float* b7   = (const float*)d_in[8];
  const float* remb = (const float*)d_in[9];
  const float* dww  = (const float*)d_in[10];
  const float* dwb  = (const float*)d_in[11];
  const float* Wq   = (const float*)d_in[12];
  const float* Wk   = (const float*)d_in[13];
  const float* Wv   = (const float*)d_in[14];
  const float* fcw  = (const float*)d_in[15];
  const float* fcb  = (const float*)d_in[16];
  const float* lnw  = (const float*)d_in[17];
  const float* lnb  = (const float*)d_in[18];
  float* out = (float*)d_out;

  char* w8 = (char*)d_ws;
  float*  Gamma = (float*)(w8);                     // 16,777,216
  float*  xm    = (float*)(w8 + 16777216);          // 12,582,912
  float*  psum  = (float*)(w8 + 29360128);          //    393,216
  ushort* xpeb  = (ushort*)(w8 + 29753344);         //  6,291,456 (bf16)
  ushort* Qb    = (ushort*)(w8 + 36044800);         // 16,777,216 (bf16, [b][h][q][dk])
  ushort* Kp    = (ushort*)(w8 + 52822016);         //  8,388,608 (bf16, [b][h][s][dk])
  ushort* Vt    = (ushort*)(w8 + 61210624);         //  8,388,608 (bf16, [b][h][dk][s])
  ushort* Ao    = (ushort*)(w8 + 69599232);         // 16,777,216 (bf16, [b][h][q][dk])
  ushort* fcwb  = (ushort*)(w8 + 86376448);         //    131,072 (bf16)
  ushort* xvb   = (ushort*)(w8 + 103284736);        //  2,097,152 (bf16)
  ushort* Wgb   = (ushort*)(w8 + 105381888);        //     32,768 (bf16)
  ushort* Wqb   = (ushort*)(w8 + 105414656);        //    131,072 (bf16)
  ushort* Wkb   = (ushort*)(w8 + 105545728);        //     98,304 (bf16)
  ushort* Wvb   = (ushort*)(w8 + 105644032);        //     98,304 (bf16)
  // conv im2col scratch lives inside Ao's region (Ao written only later by
  // attn; conv stage finishes before projections run — same-stream ordering)
  ushort* xvp   = (ushort*)(w8 + 69599232);         //  4,243,456 (bf16 hi+lo)
  ushort* wbigb = (ushort*)(w8 + 69599232 + 4243456); //  172,032 (bf16, [192][448])

  tobf_kernel<<<(B * MN * VD) / 1024, 256, 0, stream>>>(x_velocity, xvb);
  tobf5_kernel<<<240, 256, 0, stream>>>(Wg, Wgb, Wq, Wqb, Wk, Wkb, Wv, Wvb, fcw, fcwb);

  splitpad_kernel<<<(B * SPAD * VD + 255) / 256, 256, 0, stream>>>(x_velocity, xvp);
  wbig_kernel<<<D3, 448, 0, stream>>>(w3, w5, w7, wbigb);
  conv_mfma_kernel<<<B * MN / 16, 256, 0, stream>>>(xvp, wbigb, b3, b5, b7, xm);

  possum_kernel<<<MN, D3, 0, stream>>>(remb, psum);
  pe_kernel<<<B * MN, D3, 0, stream>>>(xm, psum, remb, dww, dwb, xpeb);

  proj_mfma_kernel<VD, 0, 1, 0><<<B * MN / 64, 256, 0, stream>>>(xvb, Wgb, Gamma);
  proj_mfma_kernel<SD, 4, 0, 1><<<B * L / 64, 256, 0, stream>>>(x_spatial, Wqb, Qb);
  proj_mfma_kernel<D3, 3, 0, 0><<<B * MN / 64, 256, 0, stream>>>(xpeb, Wkb, Kp);
  proj_mfma_kernel<D3, 2, 0, 0><<<B * MN / 64, 256, 0, stream>>>(xpeb, Wvb, Vt);

  attn_mfma_kernel<<<B * NH * (L / 128), 256, 0, stream>>>(Qb, Kp, Vt, Ao);
  final_mfma_kernel<<<B * L / 64, 256, 0, stream>>>(Ao, fcwb, fcb, Gamma,
                                                    x_spatial, lnw, lnb, out);
}

// Round 7
// 365.355 us; speedup vs baseline: 1.0872x; 1.0872x over previous
//
#include <hip/hip_runtime.h>

#define B   32
#define L   1024
#define MN  512
#define SD  256
#define VD  64
#define DM  256
#define D3  192
#define NH  8
#define DK  32
#define RMAX 30
#define NREL 61
#define SPAD 518   // MN + 6 (3-zero pad each side) for im2col conv windows

typedef __attribute__((ext_vector_type(8))) __bf16 bf16x8;
typedef __attribute__((ext_vector_type(4))) float  f32x4;

static __device__ __forceinline__ ushort f2bf(float f) {
  unsigned u = __float_as_uint(f);
  unsigned r = (u + 0x7FFFu + ((u >> 16) & 1u)) >> 16;
  return (ushort)r;
}
static __device__ __forceinline__ bf16x8 ldbf8(const ushort* p) {
  return __builtin_bit_cast(bf16x8, *(const uint4*)p);
}
static __device__ __forceinline__ float fexp2(float x) {
  return __builtin_amdgcn_exp2f(x);
}

// ---------------------------------------------------------------------------
// Fused small-weight converts (Wg 16, Wq 64, Wk 48, Wv 48, fcw 64 blocks).
// ---------------------------------------------------------------------------
__global__ __launch_bounds__(256) void tobf5_kernel(
    const float* __restrict__ s0, ushort* __restrict__ d0,
    const float* __restrict__ s1, ushort* __restrict__ d1,
    const float* __restrict__ s2, ushort* __restrict__ d2,
    const float* __restrict__ s3, ushort* __restrict__ d3,
    const float* __restrict__ s4, ushort* __restrict__ d4) {
  int blk = blockIdx.x;
  const float* s; ushort* d; int base;
  if (blk < 16)       { s = s0; d = d0; base = blk; }
  else if (blk < 80)  { s = s1; d = d1; base = blk - 16; }
  else if (blk < 128) { s = s2; d = d2; base = blk - 80; }
  else if (blk < 176) { s = s3; d = d3; base = blk - 128; }
  else                { s = s4; d = d4; base = blk - 176; }
  int i = (base * 256 + threadIdx.x) * 4;
  float4 v = *(const float4*)(s + i);
  *(ushort4*)(d + i) = make_ushort4(f2bf(v.x), f2bf(v.y), f2bf(v.z), f2bf(v.w));
}

// ---------------------------------------------------------------------------
// MFMA projection: wave = 16 rows, 16 col-tiles, CIN/32 k-steps.
// OMODE: 0 = f32 [row][DM]; 1 = bf16 [row][DM]; 2 = bf16 V^T [b][h][dk][s];
//        3 = bf16 K [b][h][s][dk]; 4 = bf16 Q head-major [b][h][q][dk]
// AF32: A operand read as f32 and converted in-kernel (saves a tobf pass).
// ---------------------------------------------------------------------------
template<int CIN, int OMODE, int ACT, int AF32>
__global__ __launch_bounds__(256, 2) void proj_mfma_kernel(
    const void* __restrict__ Xv, const ushort* __restrict__ Wb, void* Yv) {
  const int tid = threadIdx.x;
  const int wave = tid >> 6, lane = tid & 63;
  const int q15 = lane & 15, quad = lane >> 4;
  const int row0 = blockIdx.x * 64 + wave * 16;
  constexpr int KS = CIN / 32;

  f32x4 acc[16];
#pragma unroll
  for (int t = 0; t < 16; ++t) acc[t] = (f32x4){0.f, 0.f, 0.f, 0.f};

  const ushort* abase = (const ushort*)Xv + (size_t)(row0 + q15) * CIN + quad * 8;
  const float*  fbase = (const float*)Xv + (size_t)(row0 + q15) * CIN + quad * 8;
  const ushort* bbase = Wb + (size_t)q15 * CIN + quad * 8;
#pragma unroll 2
  for (int ks = 0; ks < KS; ++ks) {
    bf16x8 af;
    if constexpr (AF32) {
      float4 u0 = *(const float4*)(fbase + ks * 32);
      float4 u1 = *(const float4*)(fbase + ks * 32 + 4);
      uint4 p;
      p.x = (uint)f2bf(u0.x) | ((uint)f2bf(u0.y) << 16);
      p.y = (uint)f2bf(u0.z) | ((uint)f2bf(u0.w) << 16);
      p.z = (uint)f2bf(u1.x) | ((uint)f2bf(u1.y) << 16);
      p.w = (uint)f2bf(u1.z) | ((uint)f2bf(u1.w) << 16);
      af = __builtin_bit_cast(bf16x8, p);
    } else {
      af = ldbf8(abase + ks * 32);
    }
#pragma unroll
    for (int t = 0; t < 16; ++t) {
      bf16x8 bf = ldbf8(bbase + (size_t)t * 16 * CIN + ks * 32);
      acc[t] = __builtin_amdgcn_mfma_f32_16x16x32_bf16(af, bf, acc[t], 0, 0, 0);
    }
  }
#pragma unroll
  for (int reg = 0; reg < 4; ++reg) {
    const int row = row0 + quad * 4 + reg;
#pragma unroll
    for (int t = 0; t < 16; ++t) {
      int col = t * 16 + q15;
      float v = acc[t][reg];
      if (ACT == 1) v = 1.f / (1.f + __expf(-v));
      if (OMODE == 0) {
        ((float*)Yv)[(size_t)row * DM + col] = v;
      } else if (OMODE == 1) {
        ((ushort*)Yv)[(size_t)row * DM + col] = f2bf(v);
      } else if (OMODE == 2) {
        int b_ = row >> 9, s = row & 511;
        int h = t >> 1, dk = (t & 1) * 16 + q15;
        ((ushort*)Yv)[((size_t)((b_ * NH + h) * DK + dk)) * MN + s] = f2bf(v);
      } else if (OMODE == 3) {
        int b_ = row >> 9, s = row & 511;
        int h = col >> 5, dk = col & 31;
        ((ushort*)Yv)[((size_t)((b_ * NH + h) * MN + s)) * DK + dk] = f2bf(v);
      } else {
        int b_ = row >> 10, q = row & 1023;
        int h = col >> 5, dk = col & 31;
        ((ushort*)Yv)[((size_t)((b_ * NH + h) * L + q)) * DK + dk] = f2bf(v);
      }
    }
  }
}

// ---------------------------------------------------------------------------
// R14: merged K+V projection — one 512-block launch, shared A (xpeb).
// blk<256: K [b][h][s][dk]; blk>=256: V^T [b][h][dk][s].
// ---------------------------------------------------------------------------
__global__ __launch_bounds__(256, 2) void projkv_mfma_kernel(
    const ushort* __restrict__ Xb, const ushort* __restrict__ Wk,
    const ushort* __restrict__ Wv, ushort* __restrict__ Kp,
    ushort* __restrict__ Vt) {
  const int isV = blockIdx.x >> 8;
  const int blk = blockIdx.x & 255;
  const int tid = threadIdx.x;
  const int wave = tid >> 6, lane = tid & 63;
  const int q15 = lane & 15, quad = lane >> 4;
  const int row0 = blk * 64 + wave * 16;
  constexpr int KS = D3 / 32;

  f32x4 acc[16];
#pragma unroll
  for (int t = 0; t < 16; ++t) acc[t] = (f32x4){0.f, 0.f, 0.f, 0.f};

  const ushort* abase = Xb + (size_t)(row0 + q15) * D3 + quad * 8;
  const ushort* bbase = (isV ? Wv : Wk) + (size_t)q15 * D3 + quad * 8;
#pragma unroll 2
  for (int ks = 0; ks < KS; ++ks) {
    bf16x8 af = ldbf8(abase + ks * 32);
#pragma unroll
    for (int t = 0; t < 16; ++t) {
      bf16x8 bf = ldbf8(bbase + (size_t)t * 16 * D3 + ks * 32);
      acc[t] = __builtin_amdgcn_mfma_f32_16x16x32_bf16(af, bf, acc[t], 0, 0, 0);
    }
  }
#pragma unroll
  for (int reg = 0; reg < 4; ++reg) {
    const int row = row0 + quad * 4 + reg;
    const int b_ = row >> 9, s = row & 511;
#pragma unroll
    for (int t = 0; t < 16; ++t) {
      int col = t * 16 + q15;
      float v = acc[t][reg];
      if (isV) {
        int h = t >> 1, dk = (t & 1) * 16 + q15;
        Vt[((size_t)((b_ * NH + h) * DK + dk)) * MN + s] = f2bf(v);
      } else {
        int h = col >> 5, dk = col & 31;
        Kp[((size_t)((b_ * NH + h) * MN + s)) * DK + dk] = f2bf(v);
      }
    }
  }
}

// ---------------------------------------------------------------------------
// im2col conv: split-bf16 hi/lo padded planes (keeps xm f32-grade).
// ---------------------------------------------------------------------------
__global__ __launch_bounds__(256) void splitpad_kernel(
    const float* __restrict__ xv, ushort* __restrict__ xp) {
  int i = blockIdx.x * 256 + threadIdx.x;
  if (i >= B * SPAD * VD) return;
  int c = i & 63;
  int bp = i >> 6;
  int b_ = bp / SPAD, p = bp - b_ * SPAD;
  int s = p - 3;
  float v = (s >= 0 && s < MN) ? xv[((size_t)b_ * MN + s) * VD + c] : 0.f;
  ushort hi = f2bf(v);
  float vh = __uint_as_float((uint)hi << 16);
  ushort lo = f2bf(v - vh);
  xp[i] = hi;
  xp[(size_t)B * SPAD * VD + i] = lo;
}

// Wbig [192][448] bf16: row o of scale K has taps at centered k-offsets.
__global__ __launch_bounds__(448) void wbig_kernel(
    const float* __restrict__ w3, const float* __restrict__ w5,
    const float* __restrict__ w7, ushort* __restrict__ wb) {
  const int o = blockIdx.x;        // 0..191
  const int j = threadIdx.x;       // 0..447
  const int k7 = j >> 6, i = j & 63;
  const int scale = o >> 6, oo = o & 63;
  float v = 0.f;
  if (scale == 0) {
    int k = k7 - 2; if (k >= 0 && k < 3) v = w3[((size_t)oo * VD + i) * 3 + k];
  } else if (scale == 1) {
    int k = k7 - 1; if (k >= 0 && k < 5) v = w5[((size_t)oo * VD + i) * 5 + k];
  } else {
    v = w7[((size_t)oo * VD + i) * 7 + k7];
  }
  wb[(size_t)o * 448 + j] = f2bf(v);
}

// conv GEMM: M=16384 rows (windows at stride VD in padded buffer),
// N=192, K=448 (x2 for hi+lo). 16 rows/block, 4 waves x 3 col-tiles.
__global__ __launch_bounds__(256, 4) void conv_mfma_kernel(
    const ushort* __restrict__ Xp, const ushort* __restrict__ Wb,
    const float* __restrict__ b3, const float* __restrict__ b5,
    const float* __restrict__ b7, float* __restrict__ xm) {
  const int tid = threadIdx.x;
  const int wave = tid >> 6, lane = tid & 63;
  const int q15 = lane & 15, quad = lane >> 4;
  const int row0 = blockIdx.x * 16;
  const int b_ = row0 >> 9, s0 = row0 & 511;

  f32x4 acc[3];
#pragma unroll
  for (int t = 0; t < 3; ++t) acc[t] = (f32x4){0.f, 0.f, 0.f, 0.f};

  const ushort* hbase = Xp + ((size_t)b_ * SPAD + s0 + q15) * VD + quad * 8;
  const ushort* lbase = hbase + (size_t)B * SPAD * VD;
  const ushort* wbase = Wb + ((size_t)wave * 48 + q15) * 448 + quad * 8;

#pragma unroll 2
  for (int ks = 0; ks < 14; ++ks) {
    bf16x8 ah = ldbf8(hbase + ks * 32);
    bf16x8 al = ldbf8(lbase + ks * 32);
#pragma unroll
    for (int t = 0; t < 3; ++t) {
      bf16x8 bf = ldbf8(wbase + (size_t)t * 16 * 448 + ks * 32);
      acc[t] = __builtin_amdgcn_mfma_f32_16x16x32_bf16(ah, bf, acc[t], 0, 0, 0);
      acc[t] = __builtin_amdgcn_mfma_f32_16x16x32_bf16(al, bf, acc[t], 0, 0, 0);
    }
  }
#pragma unroll
  for (int t = 0; t < 3; ++t) {
    const int col = (wave * 3 + t) * 16 + q15;
    const float bias = col < 64 ? b3[col] : (col < 128 ? b5[col - 64] : b7[col - 128]);
#pragma unroll
    for (int reg = 0; reg < 4; ++reg) {
      const int row = row0 + quad * 4 + reg;
      xm[(size_t)row * D3 + col] = acc[t][reg] + bias;
    }
  }
}

// ---------------------------------------------------------------------------
// pos_sum[j, d] = sum_i emb[clip(j-i, -R, R) + R, d]
// ---------------------------------------------------------------------------
__global__ __launch_bounds__(D3) void possum_kernel(
    const float* __restrict__ emb, float* __restrict__ psum) {
  const int j = blockIdx.x, d = threadIdx.x;
  float acc = 0.f;
  for (int r = 0; r < NREL; ++r) {
    int v = r - RMAX;
    int cnt;
    if (r == 0)             cnt = max(0, MN - (j + RMAX));
    else if (r == NREL - 1) cnt = max(0, j - RMAX + 1);
    else                    cnt = (j - v >= 0 && j - v < MN) ? 1 : 0;
    acc += (float)cnt * emb[(size_t)r * D3 + d];
  }
  psum[(size_t)j * D3 + d] = acc;
}

// ---------------------------------------------------------------------------
// rel-pos-enc closed form, R14: float4-vectorized (G13), 256-thread flat.
// ---------------------------------------------------------------------------
__global__ __launch_bounds__(256) void pe4_kernel(
    const float* __restrict__ xm, const float* __restrict__ psum,
    const float* __restrict__ emb, const float* __restrict__ dww,
    const float* __restrict__ dwb, ushort* __restrict__ xpe) {
  int i = blockIdx.x * 256 + threadIdx.x;     // B*MN*48 = 786432 units
  int d4 = (i % 48) * 4;
  int bj = i / 48;
  int j = bj & 511;
  const size_t base = (size_t)bj * D3 + d4;
  f32x4 xc = *(const f32x4*)(xm + base);
  f32x4 eC = *(const f32x4*)(emb + (size_t)RMAX * D3 + d4);
  f32x4 eL = *(const f32x4*)(emb + (size_t)(RMAX - 1) * D3 + d4);
  f32x4 eR = *(const f32x4*)(emb + (size_t)(RMAX + 1) * D3 + d4);
  f32x4 ps = *(const f32x4*)(psum + (size_t)j * D3 + d4);
  f32x4 xl = (j > 0)      ? *(const f32x4*)(xm + base - D3) : (f32x4){0.f, 0.f, 0.f, 0.f};
  f32x4 xr = (j < MN - 1) ? *(const f32x4*)(xm + base + D3) : (f32x4){0.f, 0.f, 0.f, 0.f};
  ushort4 o;
  ushort* op = (ushort*)&o;
#pragma unroll
  for (int k = 0; k < 4; ++k) {
    int d = d4 + k;
    float fC = xc[k] + eC[k];
    float fL = (j > 0)      ? xl[k] + eL[k] : 0.f;
    float fR = (j < MN - 1) ? xr[k] + eR[k] : 0.f;
    float dc = fL * dww[d * 3 + 0] + fC * dww[d * 3 + 1] + fR * dww[d * 3 + 2] + dwb[d];
    op[k] = f2bf(xc[k] + (ps[k] - fC + dc) * (1.f / MN));
  }
  *(ushort4*)(xpe + base) = o;
}

// ---------------------------------------------------------------------------
// MFMA flash attention — R4's proven body (66.5us, 84 VGPR, 0 conflicts).
// R13 post-mortem: two-pass + 128-key P rows regressed (82us): row stride
// 272B = 68 words = 4 mod 32 banks -> 8-way b128 read conflict (3.1M cyc),
// and pass-1's 64 extra MFMAs + 256-op fmax chain cost what the removed
// shfl/alpha links saved. Reverted; PSTRIDE=36 layout measured conflict-free.
// ---------------------------------------------------------------------------
#define PSTRIDE 36  // ushorts per q-row (32 keys + pad)
__global__ __launch_bounds__(256, 3) void attn_mfma_kernel(
    const ushort* __restrict__ Qb, const ushort* __restrict__ Kb,
    const ushort* __restrict__ Vt, ushort* __restrict__ Ao) {
  const int blk = blockIdx.x;
  const int bh = blk & 255;        // low bits -> fixed XCD per (b,h)
  const int qc = blk >> 8;         // 0..7 (128 q rows per block)
  const int h  = bh & 7;
  const int b_ = bh >> 3;
  const int tid = threadIdx.x;
  const int wave = tid >> 6, lane = tid & 63;
  const int q15 = lane & 15, quad = lane >> 4;
  const int q0 = qc * 128 + wave * 32;

  __shared__ ushort Plds[4][2][16][PSTRIDE];   // per-wave, 2 q-tiles
  ushort* prowA = &Plds[wave][0][q15][0];
  ushort* prowB = &Plds[wave][1][q15][0];

  // Q head-major: contiguous 64B rows, adjacent rows share 128B lines
  const ushort* qrow = Qb + ((size_t)((b_ * NH + h) * L) + q0 + q15) * DK + quad * 8;
  const bf16x8 qfA = ldbf8(qrow);
  const bf16x8 qfB = ldbf8(qrow + (size_t)16 * DK);

  f32x4 o0A = {0.f, 0.f, 0.f, 0.f}, o1A = {0.f, 0.f, 0.f, 0.f};
  f32x4 o0B = {0.f, 0.f, 0.f, 0.f}, o1B = {0.f, 0.f, 0.f, 0.f};
  float mA = -1e30f, lA = 0.f, mB = -1e30f, lB = 0.f;
  // softmax in exp2 space: s2 = s * (1/sqrt(32)) * log2(e)
  const float sc2 = 0.17677669529663687f * 1.4426950408889634f;

  const ushort* kbase = Kb + (((size_t)(b_ * NH + h) * MN) + q15) * DK + quad * 8;
  const ushort* vbase = Vt + ((size_t)((b_ * NH + h) * DK) + q15) * MN;

#pragma unroll
  for (int c = 0; c < 4; ++c) {
    const int kb0 = c * 128;
    // prefetch all V fragments for this c-iter (shared by A and B tiles)
    bf16x8 av[8];
#pragma unroll
    for (int g = 0; g < 4; ++g) {
      av[g * 2]     = ldbf8(vbase + (size_t)(kb0 + g * 32 + quad * 8));
      av[g * 2 + 1] = ldbf8(vbase + (size_t)16 * MN + (kb0 + g * 32 + quad * 8));
    }
    f32x4 sA[8], sB[8];
#pragma unroll
    for (int t = 0; t < 8; ++t) {
      bf16x8 af = ldbf8(kbase + (size_t)(kb0 + t * 16) * DK);
      f32x4 z = {0.f, 0.f, 0.f, 0.f};
      sA[t] = __builtin_amdgcn_mfma_f32_16x16x32_bf16(af, qfA, z, 0, 0, 0);
      sB[t] = __builtin_amdgcn_mfma_f32_16x16x32_bf16(af, qfB, z, 0, 0, 0);
    }
    float mlA = -1e30f, mlB = -1e30f;
#pragma unroll
    for (int t = 0; t < 8; ++t)
#pragma unroll
      for (int r = 0; r < 4; ++r) {
        sA[t][r] *= sc2; mlA = fmaxf(mlA, sA[t][r]);
        sB[t][r] *= sc2; mlB = fmaxf(mlB, sB[t][r]);
      }
    mlA = fmaxf(mlA, __shfl_xor(mlA, 16));
    mlB = fmaxf(mlB, __shfl_xor(mlB, 16));
    mlA = fmaxf(mlA, __shfl_xor(mlA, 32));
    mlB = fmaxf(mlB, __shfl_xor(mlB, 32));
    float mnA = fmaxf(mA, mlA), mnB = fmaxf(mB, mlB);
    float aA = fexp2(mA - mnA), aB = fexp2(mB - mnB);
    mA = mnA; mB = mnB;
    lA *= aA; lB *= aB;
#pragma unroll
    for (int r = 0; r < 4; ++r) {
      o0A[r] *= aA; o1A[r] *= aA;
      o0B[r] *= aB; o1B[r] *= aB;
    }
    // per 32-key group: exp2 -> pack(trunc) -> tiny LDS round-trip -> PV mfma
#pragma unroll
    for (int g = 0; g < 4; ++g) {
#pragma unroll
      for (int tp = 0; tp < 2; ++tp) {
        int t = 2 * g + tp;
        float a0 = fexp2(sA[t][0] - mA), a1 = fexp2(sA[t][1] - mA);
        float a2 = fexp2(sA[t][2] - mA), a3 = fexp2(sA[t][3] - mA);
        lA += (a0 + a1) + (a2 + a3);
        uint uA01 = __builtin_amdgcn_perm(__float_as_uint(a1), __float_as_uint(a0), 0x07060302u);
        uint uA23 = __builtin_amdgcn_perm(__float_as_uint(a3), __float_as_uint(a2), 0x07060302u);
        *(uint2*)(prowA + tp * 16 + quad * 4) = make_uint2(uA01, uA23);
        float b0 = fexp2(sB[t][0] - mB), b1 = fexp2(sB[t][1] - mB);
        float b2 = fexp2(sB[t][2] - mB), b3 = fexp2(sB[t][3] - mB);
        lB += (b0 + b1) + (b2 + b3);
        uint uB01 = __builtin_amdgcn_perm(__float_as_uint(b1), __float_as_uint(b0), 0x07060302u);
        uint uB23 = __builtin_amdgcn_perm(__float_as_uint(b3), __float_as_uint(b2), 0x07060302u);
        *(uint2*)(prowB + tp * 16 + quad * 4) = make_uint2(uB01, uB23);
      }
      bf16x8 bfA = ldbf8(prowA + quad * 8);   // B[k=key_local][n=q]
      bf16x8 bfB = ldbf8(prowB + quad * 8);
      o0A = __builtin_amdgcn_mfma_f32_16x16x32_bf16(av[g * 2],     bfA, o0A, 0, 0, 0);
      o1A = __builtin_amdgcn_mfma_f32_16x16x32_bf16(av[g * 2 + 1], bfA, o1A, 0, 0, 0);
      o0B = __builtin_amdgcn_mfma_f32_16x16x32_bf16(av[g * 2],     bfB, o0B, 0, 0, 0);
      o1B = __builtin_amdgcn_mfma_f32_16x16x32_bf16(av[g * 2 + 1], bfB, o1B, 0, 0, 0);
    }
  }
  lA += __shfl_xor(lA, 16); lA += __shfl_xor(lA, 32);
  lB += __shfl_xor(lB, 16); lB += __shfl_xor(lB, 32);
  float rA = 1.f / lA, rB = 1.f / lB;
  // Ao head-major: each 128B line (rows q,q+1) fully written by this wave
  ushort* obA = Ao + ((size_t)((b_ * NH + h) * L) + q0 + q15) * DK + quad * 4;
  *(ushort4*)(obA)      = make_ushort4(f2bf(o0A[0] * rA), f2bf(o0A[1] * rA),
                                       f2bf(o0A[2] * rA), f2bf(o0A[3] * rA));
  *(ushort4*)(obA + 16) = make_ushort4(f2bf(o1A[0] * rA), f2bf(o1A[1] * rA),
                                       f2bf(o1A[2] * rA), f2bf(o1A[3] * rA));
  ushort* obB = obA + (size_t)16 * DK;
  *(ushort4*)(obB)      = make_ushort4(f2bf(o0B[0] * rB), f2bf(o0B[1] * rB),
                                       f2bf(o0B[2] * rB), f2bf(o0B[3] * rB));
  *(ushort4*)(obB + 16) = make_ushort4(f2bf(o1B[0] * rB), f2bf(o1B[1] * rB),
                                       f2bf(o1B[2] * rB), f2bf(o1B[3] * rB));
}

// ---------------------------------------------------------------------------
// Final via MFMA: fc (bf16 MFMA) + Gamma gating + residual + LayerNorm.
// Ao is head-major [b][h][q][dk]; with KS=8, k-chunk ks == head ks,
// so A-loads are abase + ks*L*DK (uniform stride). fcwb unchanged.
// ---------------------------------------------------------------------------
__global__ __launch_bounds__(256, 2) void final_mfma_kernel(
    const ushort* __restrict__ Ao, const ushort* __restrict__ fcwb,
    const float* __restrict__ fcb, const float* __restrict__ G,
    const float* __restrict__ Xs, const float* __restrict__ lnw,
    const float* __restrict__ lnb, float* __restrict__ out) {
  const int tid = threadIdx.x;
  const int wave = tid >> 6, lane = tid & 63;
  const int q15 = lane & 15, quad = lane >> 4;
  const int row0 = blockIdx.x * 64 + wave * 16;
  const int brow = row0 >> 10;            // batch (blocks are 64-row aligned)
  const int srow = (row0 & 1023) + q15;   // q within batch

  f32x4 acc[16];
#pragma unroll
  for (int t = 0; t < 16; ++t) acc[t] = (f32x4){0.f, 0.f, 0.f, 0.f};

  const ushort* abase = Ao + ((size_t)(brow * NH) * L + srow) * DK + quad * 8;
  const ushort* bbase = fcwb + (size_t)q15 * DM + quad * 8;
#pragma unroll 2
  for (int ks = 0; ks < 8; ++ks) {
    bf16x8 af = ldbf8(abase + (size_t)ks * L * DK);
#pragma unroll
    for (int t = 0; t < 16; ++t) {
      bf16x8 bf = ldbf8(bbase + (size_t)t * 16 * DM + ks * 32);
      acc[t] = __builtin_amdgcn_mfma_f32_16x16x32_bf16(af, bf, acc[t], 0, 0, 0);
    }
  }
#pragma unroll
  for (int reg = 0; reg < 4; ++reg) {
    const int grow = row0 + quad * 4 + reg;
    const int b_ = grow >> 10;
    const int gl = (grow & 1023) & 511;
    const float* gbase = G + ((size_t)b_ * MN + gl) * DM + q15;
    const float* xbase = Xs + (size_t)grow * SD + q15;
    float vv[16];
    float s1 = 0.f, s2 = 0.f;
#pragma unroll
    for (int t = 0; t < 16; ++t) {
      int col = t * 16 + q15;
      float fcv = acc[t][reg] + fcb[col];
      float v = xbase[t * 16] + gbase[t * 16] * fcv;
      vv[t] = v; s1 += v; s2 += v * v;
    }
    s1 += __shfl_xor(s1, 1); s2 += __shfl_xor(s2, 1);
    s1 += __shfl_xor(s1, 2); s2 += __shfl_xor(s2, 2);
    s1 += __shfl_xor(s1, 4); s2 += __shfl_xor(s2, 4);
    s1 += __shfl_xor(s1, 8); s2 += __shfl_xor(s2, 8);
    float mu = s1 * (1.f / DM);
    float var = s2 * (1.f / DM) - mu * mu;
    float rs = rsqrtf(var + 1e-5f);
    float* obase = out + (size_t)grow * DM + q15;
#pragma unroll
    for (int t = 0; t < 16; ++t) {
      int col = t * 16 + q15;
      obase[t * 16] = (vv[t] - mu) * rs * lnw[col] + lnb[col];
    }
  }
}

// ---------------------------------------------------------------------------
extern "C" void kernel_launch(void* const* d_in, const int* in_sizes, int n_in,
                              void* d_out, int out_size, void* d_ws, size_t ws_size,
                              hipStream_t stream) {
  const float* x_spatial  = (const float*)d_in[0];
  const float* x_velocity = (const float*)d_in[1];
  const float* Wg   = (const float*)d_in[2];
  const float* w3   = (const float*)d_in[3];
  const float* b3   = (const float*)d_in[4];
  const float* w5   = (const float*)d_in[5];
  const float* b5   = (const float*)d_in[6];
  const float* w7   = (const float*)d_in[7];
  const float* b7   = (const float*)d_in[8];
  const float* remb = (const float*)d_in[9];
  const float* dww  = (const float*)d_in[10];
  const float* dwb  = (const float*)d_in[11];
  const float* Wq   = (const float*)d_in[12];
  const float* Wk   = (const float*)d_in[13];
  const float* Wv   = (const float*)d_in[14];
  const float* fcw  = (const float*)d_in[15];
  const float* fcb  = (const float*)d_in[16];
  const float* lnw  = (const float*)d_in[17];
  const float* lnb  = (const float*)d_in[18];
  float* out = (float*)d_out;

  char* w8 = (char*)d_ws;
  float*  Gamma = (float*)(w8);                     // 16,777,216
  float*  xm    = (float*)(w8 + 16777216);          // 12,582,912
  float*  psum  = (float*)(w8 + 29360128);          //    393,216
  ushort* xpeb  = (ushort*)(w8 + 29753344);         //  6,291,456 (bf16)
  ushort* Qb    = (ushort*)(w8 + 36044800);         // 16,777,216 (bf16, [b][h][q][dk])
  ushort* Kp    = (ushort*)(w8 + 52822016);         //  8,388,608 (bf16, [b][h][s][dk])
  ushort* Vt    = (ushort*)(w8 + 61210624);         //  8,388,608 (bf16, [b][h][dk][s])
  ushort* Ao    = (ushort*)(w8 + 69599232);         // 16,777,216 (bf16, [b][h][q][dk])
  ushort* fcwb  = (ushort*)(w8 + 86376448);         //    131,072 (bf16)
  ushort* Wgb   = (ushort*)(w8 + 105381888);        //     32,768 (bf16)
  ushort* Wqb   = (ushort*)(w8 + 105414656);        //    131,072 (bf16)
  ushort* Wkb   = (ushort*)(w8 + 105545728);        //     98,304 (bf16)
  ushort* Wvb   = (ushort*)(w8 + 105644032);        //     98,304 (bf16)
  // conv im2col scratch lives inside Ao's region (Ao written only later by
  // attn; conv stage finishes before projections run — same-stream ordering)
  ushort* xvp   = (ushort*)(w8 + 69599232);         //  4,243,456 (bf16 hi+lo)
  ushort* wbigb = (ushort*)(w8 + 69599232 + 4243456); //  172,032 (bf16, [192][448])

  tobf5_kernel<<<240, 256, 0, stream>>>(Wg, Wgb, Wq, Wqb, Wk, Wkb, Wv, Wvb, fcw, fcwb);

  splitpad_kernel<<<(B * SPAD * VD + 255) / 256, 256, 0, stream>>>(x_velocity, xvp);
  wbig_kernel<<<D3, 448, 0, stream>>>(w3, w5, w7, wbigb);
  conv_mfma_kernel<<<B * MN / 16, 256, 0, stream>>>(xvp, wbigb, b3, b5, b7, xm);

  possum_kernel<<<MN, D3, 0, stream>>>(remb, psum);
  pe4_kernel<<<(B * MN * 48) / 256, 256, 0, stream>>>(xm, psum, remb, dww, dwb, xpeb);

  proj_mfma_kernel<VD, 0, 1, 1><<<B * MN / 64, 256, 0, stream>>>(x_velocity, Wgb, Gamma);
  proj_mfma_kernel<SD, 4, 0, 1><<<B * L / 64, 256, 0, stream>>>(x_spatial, Wqb, Qb);
  projkv_mfma_kernel<<<2 * B * MN / 64, 256, 0, stream>>>(xpeb, Wkb, Wvb, Kp, Vt);

  attn_mfma_kernel<<<B * NH * (L / 128), 256, 0, stream>>>(Qb, Kp, Vt, Ao);
  final_mfma_kernel<<<B * L / 64, 256, 0, stream>>>(Ao, fcwb, fcb, Gamma,
                                                    x_spatial, lnw, lnb, out);
}

// Round 8
// 337.558 us; speedup vs baseline: 1.1767x; 1.0823x over previous
//
#include <hip/hip_runtime.h>

#define B   32
#define L   1024
#define MN  512
#define SD  256
#define VD  64
#define DM  256
#define D3  192
#define NH  8
#define DK  32
#define RMAX 30
#define NREL 61
#define SPAD 518   // MN + 6 (3-zero pad each side) for im2col conv windows

typedef __attribute__((ext_vector_type(8))) __bf16 bf16x8;
typedef __attribute__((ext_vector_type(4))) float  f32x4;

static __device__ __forceinline__ ushort f2bf(float f) {
  unsigned u = __float_as_uint(f);
  unsigned r = (u + 0x7FFFu + ((u >> 16) & 1u)) >> 16;
  return (ushort)r;
}
static __device__ __forceinline__ bf16x8 ldbf8(const ushort* p) {
  return __builtin_bit_cast(bf16x8, *(const uint4*)p);
}
static __device__ __forceinline__ float fexp2(float x) {
  return __builtin_amdgcn_exp2f(x);
}

// ---------------------------------------------------------------------------
// R15 prep: tobf5 + splitpad + wbig + possum fused (all input-only readers).
// grid = 240 + 4144 + 192 + 512 = 5088 blocks x 256 threads.
// ---------------------------------------------------------------------------
__global__ __launch_bounds__(256) void prep_kernel(
    const float* __restrict__ Wg, ushort* __restrict__ Wgb,
    const float* __restrict__ Wq, ushort* __restrict__ Wqb,
    const float* __restrict__ Wk, ushort* __restrict__ Wkb,
    const float* __restrict__ Wv, ushort* __restrict__ Wvb,
    const float* __restrict__ fcw, ushort* __restrict__ fcwb,
    const float* __restrict__ xv, ushort* __restrict__ xp,
    const float* __restrict__ w3, const float* __restrict__ w5,
    const float* __restrict__ w7, ushort* __restrict__ wb,
    const float* __restrict__ emb, float* __restrict__ psum) {
  int blk = blockIdx.x;
  if (blk < 240) {
    const float* s; ushort* d; int base;
    if (blk < 16)       { s = Wg;  d = Wgb;  base = blk; }
    else if (blk < 80)  { s = Wq;  d = Wqb;  base = blk - 16; }
    else if (blk < 128) { s = Wk;  d = Wkb;  base = blk - 80; }
    else if (blk < 176) { s = Wv;  d = Wvb;  base = blk - 128; }
    else                { s = fcw; d = fcwb; base = blk - 176; }
    int i = (base * 256 + threadIdx.x) * 4;
    float4 v = *(const float4*)(s + i);
    *(ushort4*)(d + i) = make_ushort4(f2bf(v.x), f2bf(v.y), f2bf(v.z), f2bf(v.w));
  } else if (blk < 240 + 4144) {
    int i = (blk - 240) * 256 + threadIdx.x;
    if (i < B * SPAD * VD) {
      int c = i & 63;
      int bp = i >> 6;
      int b_ = bp / SPAD, p = bp - b_ * SPAD;
      int s = p - 3;
      float v = (s >= 0 && s < MN) ? xv[((size_t)b_ * MN + s) * VD + c] : 0.f;
      ushort hi = f2bf(v);
      float vh = __uint_as_float((uint)hi << 16);
      ushort lo = f2bf(v - vh);
      xp[i] = hi;
      xp[(size_t)B * SPAD * VD + i] = lo;
    }
  } else if (blk < 240 + 4144 + 192) {
    const int o = blk - (240 + 4144);     // 0..191
    const int scale = o >> 6, oo = o & 63;
    for (int j = threadIdx.x; j < 448; j += 256) {
      const int k7 = j >> 6, i = j & 63;
      float v = 0.f;
      if (scale == 0) {
        int k = k7 - 2; if (k >= 0 && k < 3) v = w3[((size_t)oo * VD + i) * 3 + k];
      } else if (scale == 1) {
        int k = k7 - 1; if (k >= 0 && k < 5) v = w5[((size_t)oo * VD + i) * 5 + k];
      } else {
        v = w7[((size_t)oo * VD + i) * 7 + k7];
      }
      wb[(size_t)o * 448 + j] = f2bf(v);
    }
  } else {
    const int j = blk - (240 + 4144 + 192);  // 0..511
    const int d = threadIdx.x;
    if (d < D3) {
      float acc = 0.f;
      for (int r = 0; r < NREL; ++r) {
        int v = r - RMAX;
        int cnt;
        if (r == 0)             cnt = max(0, MN - (j + RMAX));
        else if (r == NREL - 1) cnt = max(0, j - RMAX + 1);
        else                    cnt = (j - v >= 0 && j - v < MN) ? 1 : 0;
        acc += (float)cnt * emb[(size_t)r * D3 + d];
      }
      psum[(size_t)j * D3 + d] = acc;
    }
  }
}

// ---------------------------------------------------------------------------
// Shared MFMA projection body: 16 rows/wave, 16 col-tiles, CIN/32 k-steps.
// OMODE: 0 = f32 [row][DM] (sigmoid); 2 = bf16 V^T [b][h][dk][s];
//        3 = bf16 K [b][h][s][dk]; 4 = bf16 Q head-major [b][h][q][dk]
// ---------------------------------------------------------------------------
template<int CIN, int OMODE, int ACT, int AF32>
static __device__ __forceinline__ void proj_body(
    int blk, const void* __restrict__ Xv, const ushort* __restrict__ Wb,
    void* __restrict__ Yv, int tid) {
  const int wave = tid >> 6, lane = tid & 63;
  const int q15 = lane & 15, quad = lane >> 4;
  const int row0 = blk * 64 + wave * 16;
  constexpr int KS = CIN / 32;

  f32x4 acc[16];
#pragma unroll
  for (int t = 0; t < 16; ++t) acc[t] = (f32x4){0.f, 0.f, 0.f, 0.f};

  const ushort* abase = (const ushort*)Xv + (size_t)(row0 + q15) * CIN + quad * 8;
  const float*  fbase = (const float*)Xv + (size_t)(row0 + q15) * CIN + quad * 8;
  const ushort* bbase = Wb + (size_t)q15 * CIN + quad * 8;
#pragma unroll 2
  for (int ks = 0; ks < KS; ++ks) {
    bf16x8 af;
    if constexpr (AF32) {
      float4 u0 = *(const float4*)(fbase + ks * 32);
      float4 u1 = *(const float4*)(fbase + ks * 32 + 4);
      uint4 p;
      p.x = (uint)f2bf(u0.x) | ((uint)f2bf(u0.y) << 16);
      p.y = (uint)f2bf(u0.z) | ((uint)f2bf(u0.w) << 16);
      p.z = (uint)f2bf(u1.x) | ((uint)f2bf(u1.y) << 16);
      p.w = (uint)f2bf(u1.z) | ((uint)f2bf(u1.w) << 16);
      af = __builtin_bit_cast(bf16x8, p);
    } else {
      af = ldbf8(abase + ks * 32);
    }
#pragma unroll
    for (int t = 0; t < 16; ++t) {
      bf16x8 bf = ldbf8(bbase + (size_t)t * 16 * CIN + ks * 32);
      acc[t] = __builtin_amdgcn_mfma_f32_16x16x32_bf16(af, bf, acc[t], 0, 0, 0);
    }
  }
#pragma unroll
  for (int reg = 0; reg < 4; ++reg) {
    const int row = row0 + quad * 4 + reg;
#pragma unroll
    for (int t = 0; t < 16; ++t) {
      int col = t * 16 + q15;
      float v = acc[t][reg];
      if (ACT == 1) v = 1.f / (1.f + __expf(-v));
      if (OMODE == 0) {
        ((float*)Yv)[(size_t)row * DM + col] = v;
      } else if (OMODE == 2) {
        int b_ = row >> 9, s = row & 511;
        int h = t >> 1, dk = (t & 1) * 16 + q15;
        ((ushort*)Yv)[((size_t)((b_ * NH + h) * DK + dk)) * MN + s] = f2bf(v);
      } else if (OMODE == 3) {
        int b_ = row >> 9, s = row & 511;
        int h = col >> 5, dk = col & 31;
        ((ushort*)Yv)[((size_t)((b_ * NH + h) * MN + s)) * DK + dk] = f2bf(v);
      } else {
        int b_ = row >> 10, q = row & 1023;
        int h = col >> 5, dk = col & 31;
        ((ushort*)Yv)[((size_t)((b_ * NH + h) * L + q)) * DK + dk] = f2bf(v);
      }
    }
  }
}

// ---------------------------------------------------------------------------
// R15: all four projections in ONE 1280-block launch (Gamma 256 | Q 512 |
// K 256 | V 256). The stages are mutually independent; serial dispatch ran
// them at 1-2 blocks/CU each (grid-limited, latency-bound). Combined grid
// co-schedules their waves -> higher per-SIMD ILP, 2 fewer launches.
// ---------------------------------------------------------------------------
__global__ __launch_bounds__(256, 2) void proj_all_kernel(
    const float* __restrict__ xv, const ushort* __restrict__ Wgb,
    float* __restrict__ Gamma,
    const float* __restrict__ xs, const ushort* __restrict__ Wqb,
    ushort* __restrict__ Qb,
    const ushort* __restrict__ xpeb, const ushort* __restrict__ Wkb,
    ushort* __restrict__ Kp, const ushort* __restrict__ Wvb,
    ushort* __restrict__ Vt) {
  const int blk = blockIdx.x;
  const int tid = threadIdx.x;
  if (blk < 256) {
    proj_body<VD, 0, 1, 1>(blk, xv, Wgb, Gamma, tid);
  } else if (blk < 768) {
    proj_body<SD, 4, 0, 1>(blk - 256, xs, Wqb, Qb, tid);
  } else if (blk < 1024) {
    proj_body<D3, 3, 0, 0>(blk - 768, xpeb, Wkb, Kp, tid);
  } else {
    proj_body<D3, 2, 0, 0>(blk - 1024, xpeb, Wvb, Vt, tid);
  }
}

// ---------------------------------------------------------------------------
// conv GEMM: M=16384 rows (windows at stride VD in padded buffer),
// N=192, K=448 (x2 for hi+lo). 16 rows/block, 4 waves x 3 col-tiles.
// ---------------------------------------------------------------------------
__global__ __launch_bounds__(256, 4) void conv_mfma_kernel(
    const ushort* __restrict__ Xp, const ushort* __restrict__ Wb,
    const float* __restrict__ b3, const float* __restrict__ b5,
    const float* __restrict__ b7, float* __restrict__ xm) {
  const int tid = threadIdx.x;
  const int wave = tid >> 6, lane = tid & 63;
  const int q15 = lane & 15, quad = lane >> 4;
  const int row0 = blockIdx.x * 16;
  const int b_ = row0 >> 9, s0 = row0 & 511;

  f32x4 acc[3];
#pragma unroll
  for (int t = 0; t < 3; ++t) acc[t] = (f32x4){0.f, 0.f, 0.f, 0.f};

  const ushort* hbase = Xp + ((size_t)b_ * SPAD + s0 + q15) * VD + quad * 8;
  const ushort* lbase = hbase + (size_t)B * SPAD * VD;
  const ushort* wbase = Wb + ((size_t)wave * 48 + q15) * 448 + quad * 8;

#pragma unroll 2
  for (int ks = 0; ks < 14; ++ks) {
    bf16x8 ah = ldbf8(hbase + ks * 32);
    bf16x8 al = ldbf8(lbase + ks * 32);
#pragma unroll
    for (int t = 0; t < 3; ++t) {
      bf16x8 bf = ldbf8(wbase + (size_t)t * 16 * 448 + ks * 32);
      acc[t] = __builtin_amdgcn_mfma_f32_16x16x32_bf16(ah, bf, acc[t], 0, 0, 0);
      acc[t] = __builtin_amdgcn_mfma_f32_16x16x32_bf16(al, bf, acc[t], 0, 0, 0);
    }
  }
#pragma unroll
  for (int t = 0; t < 3; ++t) {
    const int col = (wave * 3 + t) * 16 + q15;
    const float bias = col < 64 ? b3[col] : (col < 128 ? b5[col - 64] : b7[col - 128]);
#pragma unroll
    for (int reg = 0; reg < 4; ++reg) {
      const int row = row0 + quad * 4 + reg;
      xm[(size_t)row * D3 + col] = acc[t][reg] + bias;
    }
  }
}

// ---------------------------------------------------------------------------
// rel-pos-enc closed form, float4-vectorized (G13), 256-thread flat.
// ---------------------------------------------------------------------------
__global__ __launch_bounds__(256) void pe4_kernel(
    const float* __restrict__ xm, const float* __restrict__ psum,
    const float* __restrict__ emb, const float* __restrict__ dww,
    const float* __restrict__ dwb, ushort* __restrict__ xpe) {
  int i = blockIdx.x * 256 + threadIdx.x;     // B*MN*48 = 786432 units
  int d4 = (i % 48) * 4;
  int bj = i / 48;
  int j = bj & 511;
  const size_t base = (size_t)bj * D3 + d4;
  f32x4 xc = *(const f32x4*)(xm + base);
  f32x4 eC = *(const f32x4*)(emb + (size_t)RMAX * D3 + d4);
  f32x4 eL = *(const f32x4*)(emb + (size_t)(RMAX - 1) * D3 + d4);
  f32x4 eR = *(const f32x4*)(emb + (size_t)(RMAX + 1) * D3 + d4);
  f32x4 ps = *(const f32x4*)(psum + (size_t)j * D3 + d4);
  f32x4 xl = (j > 0)      ? *(const f32x4*)(xm + base - D3) : (f32x4){0.f, 0.f, 0.f, 0.f};
  f32x4 xr = (j < MN - 1) ? *(const f32x4*)(xm + base + D3) : (f32x4){0.f, 0.f, 0.f, 0.f};
  ushort4 o;
  ushort* op = (ushort*)&o;
#pragma unroll
  for (int k = 0; k < 4; ++k) {
    int d = d4 + k;
    float fC = xc[k] + eC[k];
    float fL = (j > 0)      ? xl[k] + eL[k] : 0.f;
    float fR = (j < MN - 1) ? xr[k] + eR[k] : 0.f;
    float dc = fL * dww[d * 3 + 0] + fC * dww[d * 3 + 1] + fR * dww[d * 3 + 2] + dwb[d];
    op[k] = f2bf(xc[k] + (ps[k] - fC + dc) * (1.f / MN));
  }
  *(ushort4*)(xpe + base) = o;
}

// ---------------------------------------------------------------------------
// MFMA flash attention — R4's proven body (65us, 84 VGPR, 0 conflicts).
// Dual q-tile ILP; head-major Q/Ao; PSTRIDE=36 conflict-free P staging.
// ---------------------------------------------------------------------------
#define PSTRIDE 36  // ushorts per q-row (32 keys + pad)
__global__ __launch_bounds__(256, 3) void attn_mfma_kernel(
    const ushort* __restrict__ Qb, const ushort* __restrict__ Kb,
    const ushort* __restrict__ Vt, ushort* __restrict__ Ao) {
  const int blk = blockIdx.x;
  const int bh = blk & 255;        // low bits -> fixed XCD per (b,h)
  const int qc = blk >> 8;         // 0..7 (128 q rows per block)
  const int h  = bh & 7;
  const int b_ = bh >> 3;
  const int tid = threadIdx.x;
  const int wave = tid >> 6, lane = tid & 63;
  const int q15 = lane & 15, quad = lane >> 4;
  const int q0 = qc * 128 + wave * 32;

  __shared__ ushort Plds[4][2][16][PSTRIDE];   // per-wave, 2 q-tiles
  ushort* prowA = &Plds[wave][0][q15][0];
  ushort* prowB = &Plds[wave][1][q15][0];

  // Q head-major: contiguous 64B rows, adjacent rows share 128B lines
  const ushort* qrow = Qb + ((size_t)((b_ * NH + h) * L) + q0 + q15) * DK + quad * 8;
  const bf16x8 qfA = ldbf8(qrow);
  const bf16x8 qfB = ldbf8(qrow + (size_t)16 * DK);

  f32x4 o0A = {0.f, 0.f, 0.f, 0.f}, o1A = {0.f, 0.f, 0.f, 0.f};
  f32x4 o0B = {0.f, 0.f, 0.f, 0.f}, o1B = {0.f, 0.f, 0.f, 0.f};
  float mA = -1e30f, lA = 0.f, mB = -1e30f, lB = 0.f;
  // softmax in exp2 space: s2 = s * (1/sqrt(32)) * log2(e)
  const float sc2 = 0.17677669529663687f * 1.4426950408889634f;

  const ushort* kbase = Kb + (((size_t)(b_ * NH + h) * MN) + q15) * DK + quad * 8;
  const ushort* vbase = Vt + ((size_t)((b_ * NH + h) * DK) + q15) * MN;

#pragma unroll
  for (int c = 0; c < 4; ++c) {
    const int kb0 = c * 128;
    // prefetch all V fragments for this c-iter (shared by A and B tiles)
    bf16x8 av[8];
#pragma unroll
    for (int g = 0; g < 4; ++g) {
      av[g * 2]     = ldbf8(vbase + (size_t)(kb0 + g * 32 + quad * 8));
      av[g * 2 + 1] = ldbf8(vbase + (size_t)16 * MN + (kb0 + g * 32 + quad * 8));
    }
    f32x4 sA[8], sB[8];
#pragma unroll
    for (int t = 0; t < 8; ++t) {
      bf16x8 af = ldbf8(kbase + (size_t)(kb0 + t * 16) * DK);
      f32x4 z = {0.f, 0.f, 0.f, 0.f};
      sA[t] = __builtin_amdgcn_mfma_f32_16x16x32_bf16(af, qfA, z, 0, 0, 0);
      sB[t] = __builtin_amdgcn_mfma_f32_16x16x32_bf16(af, qfB, z, 0, 0, 0);
    }
    float mlA = -1e30f, mlB = -1e30f;
#pragma unroll
    for (int t = 0; t < 8; ++t)
#pragma unroll
      for (int r = 0; r < 4; ++r) {
        sA[t][r] *= sc2; mlA = fmaxf(mlA, sA[t][r]);
        sB[t][r] *= sc2; mlB = fmaxf(mlB, sB[t][r]);
      }
    mlA = fmaxf(mlA, __shfl_xor(mlA, 16));
    mlB = fmaxf(mlB, __shfl_xor(mlB, 16));
    mlA = fmaxf(mlA, __shfl_xor(mlA, 32));
    mlB = fmaxf(mlB, __shfl_xor(mlB, 32));
    float mnA = fmaxf(mA, mlA), mnB = fmaxf(mB, mlB);
    float aA = fexp2(mA - mnA), aB = fexp2(mB - mnB);
    mA = mnA; mB = mnB;
    lA *= aA; lB *= aB;
#pragma unroll
    for (int r = 0; r < 4; ++r) {
      o0A[r] *= aA; o1A[r] *= aA;
      o0B[r] *= aB; o1B[r] *= aB;
    }
    // per 32-key group: exp2 -> pack(trunc) -> tiny LDS round-trip -> PV mfma
#pragma unroll
    for (int g = 0; g < 4; ++g) {
#pragma unroll
      for (int tp = 0; tp < 2; ++tp) {
        int t = 2 * g + tp;
        float a0 = fexp2(sA[t][0] - mA), a1 = fexp2(sA[t][1] - mA);
        float a2 = fexp2(sA[t][2] - mA), a3 = fexp2(sA[t][3] - mA);
        lA += (a0 + a1) + (a2 + a3);
        uint uA01 = __builtin_amdgcn_perm(__float_as_uint(a1), __float_as_uint(a0), 0x07060302u);
        uint uA23 = __builtin_amdgcn_perm(__float_as_uint(a3), __float_as_uint(a2), 0x07060302u);
        *(uint2*)(prowA + tp * 16 + quad * 4) = make_uint2(uA01, uA23);
        float b0 = fexp2(sB[t][0] - mB), b1 = fexp2(sB[t][1] - mB);
        float b2 = fexp2(sB[t][2] - mB), b3 = fexp2(sB[t][3] - mB);
        lB += (b0 + b1) + (b2 + b3);
        uint uB01 = __builtin_amdgcn_perm(__float_as_uint(b1), __float_as_uint(b0), 0x07060302u);
        uint uB23 = __builtin_amdgcn_perm(__float_as_uint(b3), __float_as_uint(b2), 0x07060302u);
        *(uint2*)(prowB + tp * 16 + quad * 4) = make_uint2(uB01, uB23);
      }
      bf16x8 bfA = ldbf8(prowA + quad * 8);   // B[k=key_local][n=q]
      bf16x8 bfB = ldbf8(prowB + quad * 8);
      o0A = __builtin_amdgcn_mfma_f32_16x16x32_bf16(av[g * 2],     bfA, o0A, 0, 0, 0);
      o1A = __builtin_amdgcn_mfma_f32_16x16x32_bf16(av[g * 2 + 1], bfA, o1A, 0, 0, 0);
      o0B = __builtin_amdgcn_mfma_f32_16x16x32_bf16(av[g * 2],     bfB, o0B, 0, 0, 0);
      o1B = __builtin_amdgcn_mfma_f32_16x16x32_bf16(av[g * 2 + 1], bfB, o1B, 0, 0, 0);
    }
  }
  lA += __shfl_xor(lA, 16); lA += __shfl_xor(lA, 32);
  lB += __shfl_xor(lB, 16); lB += __shfl_xor(lB, 32);
  float rA = 1.f / lA, rB = 1.f / lB;
  // Ao head-major: each 128B line (rows q,q+1) fully written by this wave
  ushort* obA = Ao + ((size_t)((b_ * NH + h) * L) + q0 + q15) * DK + quad * 4;
  *(ushort4*)(obA)      = make_ushort4(f2bf(o0A[0] * rA), f2bf(o0A[1] * rA),
                                       f2bf(o0A[2] * rA), f2bf(o0A[3] * rA));
  *(ushort4*)(obA + 16) = make_ushort4(f2bf(o1A[0] * rA), f2bf(o1A[1] * rA),
                                       f2bf(o1A[2] * rA), f2bf(o1A[3] * rA));
  ushort* obB = obA + (size_t)16 * DK;
  *(ushort4*)(obB)      = make_ushort4(f2bf(o0B[0] * rB), f2bf(o0B[1] * rB),
                                       f2bf(o0B[2] * rB), f2bf(o0B[3] * rB));
  *(ushort4*)(obB + 16) = make_ushort4(f2bf(o1B[0] * rB), f2bf(o1B[1] * rB),
                                       f2bf(o1B[2] * rB), f2bf(o1B[3] * rB));
}

// ---------------------------------------------------------------------------
// Final via MFMA: fc (bf16 MFMA) + Gamma gating + residual + LayerNorm.
// Ao is head-major [b][h][q][dk]; with KS=8, k-chunk ks == head ks,
// so A-loads are abase + ks*L*DK (uniform stride). fcwb unchanged.
// ---------------------------------------------------------------------------
__global__ __launch_bounds__(256, 2) void final_mfma_kernel(
    const ushort* __restrict__ Ao, const ushort* __restrict__ fcwb,
    const float* __restrict__ fcb, const float* __restrict__ G,
    const float* __restrict__ Xs, const float* __restrict__ lnw,
    const float* __restrict__ lnb, float* __restrict__ out) {
  const int tid = threadIdx.x;
  const int wave = tid >> 6, lane = tid & 63;
  const int q15 = lane & 15, quad = lane >> 4;
  const int row0 = blockIdx.x * 64 + wave * 16;
  const int brow = row0 >> 10;            // batch (blocks are 64-row aligned)
  const int srow = (row0 & 1023) + q15;   // q within batch

  f32x4 acc[16];
#pragma unroll
  for (int t = 0; t < 16; ++t) acc[t] = (f32x4){0.f, 0.f, 0.f, 0.f};

  const ushort* abase = Ao + ((size_t)(brow * NH) * L + srow) * DK + quad * 8;
  const ushort* bbase = fcwb + (size_t)q15 * DM + quad * 8;
#pragma unroll 2
  for (int ks = 0; ks < 8; ++ks) {
    bf16x8 af = ldbf8(abase + (size_t)ks * L * DK);
#pragma unroll
    for (int t = 0; t < 16; ++t) {
      bf16x8 bf = ldbf8(bbase + (size_t)t * 16 * DM + ks * 32);
      acc[t] = __builtin_amdgcn_mfma_f32_16x16x32_bf16(af, bf, acc[t], 0, 0, 0);
    }
  }
#pragma unroll
  for (int reg = 0; reg < 4; ++reg) {
    const int grow = row0 + quad * 4 + reg;
    const int b_ = grow >> 10;
    const int gl = (grow & 1023) & 511;
    const float* gbase = G + ((size_t)b_ * MN + gl) * DM + q15;
    const float* xbase = Xs + (size_t)grow * SD + q15;
    float vv[16];
    float s1 = 0.f, s2 = 0.f;
#pragma unroll
    for (int t = 0; t < 16; ++t) {
      int col = t * 16 + q15;
      float fcv = acc[t][reg] + fcb[col];
      float v = xbase[t * 16] + gbase[t * 16] * fcv;
      vv[t] = v; s1 += v; s2 += v * v;
    }
    s1 += __shfl_xor(s1, 1); s2 += __shfl_xor(s2, 1);
    s1 += __shfl_xor(s1, 2); s2 += __shfl_xor(s2, 2);
    s1 += __shfl_xor(s1, 4); s2 += __shfl_xor(s2, 4);
    s1 += __shfl_xor(s1, 8); s2 += __shfl_xor(s2, 8);
    float mu = s1 * (1.f / DM);
    float var = s2 * (1.f / DM) - mu * mu;
    float rs = rsqrtf(var + 1e-5f);
    float* obase = out + (size_t)grow * DM + q15;
#pragma unroll
    for (int t = 0; t < 16; ++t) {
      int col = t * 16 + q15;
      obase[t * 16] = (vv[t] - mu) * rs * lnw[col] + lnb[col];
    }
  }
}

// ---------------------------------------------------------------------------
extern "C" void kernel_launch(void* const* d_in, const int* in_sizes, int n_in,
                              void* d_out, int out_size, void* d_ws, size_t ws_size,
                              hipStream_t stream) {
  const float* x_spatial  = (const float*)d_in[0];
  const float* x_velocity = (const float*)d_in[1];
  const float* Wg   = (const float*)d_in[2];
  const float* w3   = (const float*)d_in[3];
  const float* b3   = (const float*)d_in[4];
  const float* w5   = (const float*)d_in[5];
  const float* b5   = (const float*)d_in[6];
  const float* w7   = (const float*)d_in[7];
  const float* b7   = (const float*)d_in[8];
  const float* remb = (const float*)d_in[9];
  const float* dww  = (const float*)d_in[10];
  const float* dwb  = (const float*)d_in[11];
  const float* Wq   = (const float*)d_in[12];
  const float* Wk   = (const float*)d_in[13];
  const float* Wv   = (const float*)d_in[14];
  const float* fcw  = (const float*)d_in[15];
  const float* fcb  = (const float*)d_in[16];
  const float* lnw  = (const float*)d_in[17];
  const float* lnb  = (const float*)d_in[18];
  float* out = (float*)d_out;

  char* w8 = (char*)d_ws;
  float*  Gamma = (float*)(w8);                     // 16,777,216
  float*  xm    = (float*)(w8 + 16777216);          // 12,582,912
  float*  psum  = (float*)(w8 + 29360128);          //    393,216
  ushort* xpeb  = (ushort*)(w8 + 29753344);         //  6,291,456 (bf16)
  ushort* Qb    = (ushort*)(w8 + 36044800);         // 16,777,216 (bf16, [b][h][q][dk])
  ushort* Kp    = (ushort*)(w8 + 52822016);         //  8,388,608 (bf16, [b][h][s][dk])
  ushort* Vt    = (ushort*)(w8 + 61210624);         //  8,388,608 (bf16, [b][h][dk][s])
  ushort* Ao    = (ushort*)(w8 + 69599232);         // 16,777,216 (bf16, [b][h][q][dk])
  ushort* fcwb  = (ushort*)(w8 + 86376448);         //    131,072 (bf16)
  ushort* Wgb   = (ushort*)(w8 + 105381888);        //     32,768 (bf16)
  ushort* Wqb   = (ushort*)(w8 + 105414656);        //    131,072 (bf16)
  ushort* Wkb   = (ushort*)(w8 + 105545728);        //     98,304 (bf16)
  ushort* Wvb   = (ushort*)(w8 + 105644032);        //     98,304 (bf16)
  // conv im2col scratch lives inside Ao's region (Ao written only later by
  // attn; conv stage finishes before projections run — same-stream ordering)
  ushort* xvp   = (ushort*)(w8 + 69599232);         //  4,243,456 (bf16 hi+lo)
  ushort* wbigb = (ushort*)(w8 + 69599232 + 4243456); //  172,032 (bf16, [192][448])

  prep_kernel<<<240 + 4144 + 192 + 512, 256, 0, stream>>>(
      Wg, Wgb, Wq, Wqb, Wk, Wkb, Wv, Wvb, fcw, fcwb,
      x_velocity, xvp, w3, w5, w7, wbigb, remb, psum);

  conv_mfma_kernel<<<B * MN / 16, 256, 0, stream>>>(xvp, wbigb, b3, b5, b7, xm);
  pe4_kernel<<<(B * MN * 48) / 256, 256, 0, stream>>>(xm, psum, remb, dww, dwb, xpeb);

  proj_all_kernel<<<1280, 256, 0, stream>>>(
      x_velocity, Wgb, Gamma, x_spatial, Wqb, Qb, xpeb, Wkb, Kp, Wvb, Vt);

  attn_mfma_kernel<<<B * NH * (L / 128), 256, 0, stream>>>(Qb, Kp, Vt, Ao);
  final_mfma_kernel<<<B * L / 64, 256, 0, stream>>>(Ao, fcwb, fcb, Gamma,
                                                    x_spatial, lnw, lnb, out);
}